// Round 5
// baseline (120.880 us; speedup 1.0000x reference)
//
#include <hip/hip_runtime.h>

#define BLK 256
#define NB  8                  // batch rows per block
#define NV4 ((NB * 169) / 4)   // 338 float4 outputs per block (1352 floats, 16B-aligned chunks)

typedef float v4f __attribute__((ext_vector_type(4)));

__global__ __launch_bounds__(BLK) void cone_fused_kernel(
    const float* __restrict__ eyes,
    const float* __restrict__ v,
    const float* __restrict__ R,
    const float* __restrict__ t,
    const float* __restrict__ alpha,
    float* __restrict__ out,
    int B, int total4)
{
    __shared__ float c[NB][6];
    const int tid = threadIdx.x;
    const int b0  = blockIdx.x * NB;

    // ---- Phase 1: 8 lanes build the quadratic-form coefficients ----
    if (tid < NB) {
        const int b = b0 + tid;
        if (b < B) {
            float vx = v[b*3+0], vy = v[b*3+1], vz = v[b*3+2];
            float n  = sqrtf(vx*vx + vy*vy + vz*vz);
            n = fmaxf(n, 1e-14f);
            const float inv = 1.0f / n;
            vx *= inv; vy *= inv; vz *= inv;
            const float a = alpha[b];

            // W rows: w0 = R[:,0], w1 = R[:,1], w2 = t - eyes  (R row-major [3][3])
            const float* Rb = R + (size_t)b * 9;
            const float w0x = Rb[0], w0y = Rb[3], w0z = Rb[6];
            const float w1x = Rb[1], w1y = Rb[4], w1z = Rb[7];
            const float w2x = t[b*3+0] - eyes[b*3+0];
            const float w2y = t[b*3+1] - eyes[b*3+1];
            const float w2z = t[b*3+2] - eyes[b*3+2];

            // sigma[a][c] = (vn.w_a)(vn.w_c) - alpha*(w_a.w_c)
            const float d0 = vx*w0x + vy*w0y + vz*w0z;
            const float d1 = vx*w1x + vy*w1y + vz*w1z;
            const float d2 = vx*w2x + vy*w2y + vz*w2z;

            c[tid][0] = d0*d0 - a*(w0x*w0x + w0y*w0y + w0z*w0z);          // s00
            c[tid][1] = d1*d1 - a*(w1x*w1x + w1y*w1y + w1z*w1z);          // s11
            c[tid][2] = d2*d2 - a*(w2x*w2x + w2y*w2y + w2z*w2z);          // s22
            c[tid][3] = 2.0f * (d0*d1 - a*(w0x*w1x + w0y*w1y + w0z*w1z)); // 2 s01
            c[tid][4] = 2.0f * (d0*d2 - a*(w0x*w2x + w0y*w2y + w0z*w2z)); // 2 s02
            c[tid][5] = 2.0f * (d1*d2 - a*(w1x*w2x + w1y*w2y + w1z*w2z)); // 2 s12
        }
    }
    __syncthreads();

    // ---- Phase 2: 338 coalesced nontemporal float4 stores per block ----
    const size_t base4 = (size_t)blockIdx.x * NV4;
    #pragma unroll
    for (int r = 0; r < 2; ++r) {
        const int idx = tid + r * BLK;
        if (idx < NV4 && (int)(base4 + idx) < total4) {
            const int lf = idx * 4;                 // local float index, < 1352
            // bl = lf/169 : (lf*388)>>16 exact for lf < ~2000 (boundaries verified)
            int bl = (lf * 388) >> 16;
            int k  = lf - 169 * bl;

            float s00 = c[bl][0], s11 = c[bl][1], s22 = c[bl][2];
            float t01 = c[bl][3], t02 = c[bl][4], t12 = c[bl][5];

            v4f rv;
            #pragma unroll
            for (int e = 0; e < 4; ++e) {
                if (k == 169) {                     // row-boundary crossing (169 % 4 != 0)
                    ++bl; k = 0;
                    s00 = c[bl][0]; s11 = c[bl][1]; s22 = c[bl][2];
                    t01 = c[bl][3]; t02 = c[bl][4]; t12 = c[bl][5];
                }
                // iq = k/13 exact for k<169 (e=1); j = k%13
                const int iq = (k * 20165) >> 18;
                const int j  = k - 13 * iq;
                const float px = (float)(iq - 6) * (1.0f / 6.0f);
                const float py = (float)(j  - 6) * (1.0f / 6.0f);
                rv[e] = s22 + px * (s00 * px + t01 * py + t02)
                            + py * (s11 * py + t12);
                ++k;
            }
            __builtin_nontemporal_store(rv, (v4f*)out + base4 + idx);
        }
    }
}

extern "C" void kernel_launch(void* const* d_in, const int* in_sizes, int n_in,
                              void* d_out, int out_size, void* d_ws, size_t ws_size,
                              hipStream_t stream) {
    const float* eyes  = (const float*)d_in[0];
    const float* v     = (const float*)d_in[1];
    const float* R     = (const float*)d_in[2];
    const float* t     = (const float*)d_in[3];
    const float* alpha = (const float*)d_in[4];
    float* out = (float*)d_out;

    const int B = in_sizes[4];                 // alpha has B elements
    const int total4 = out_size / 4;           // B*169/4 float4s
    const int grid = (B + NB - 1) / NB;        // 16384 blocks for B=131072

    cone_fused_kernel<<<grid, BLK, 0, stream>>>(eyes, v, R, t, alpha, out, B, total4);
}

// Round 6
// 113.664 us; speedup vs baseline: 1.0635x; 1.0635x over previous
//
#include <hip/hip_runtime.h>

#define BLK 256
#define NB  256                 // batch rows per block (one per thread in phase 1)
#define NV4 ((NB * 169) / 4)    // 10816 float4 outputs per block
#define NIT ((NV4 + BLK - 1) / BLK)   // 43 store iterations (last partial: 64 lanes)

typedef float v4f __attribute__((ext_vector_type(4)));

__global__ __launch_bounds__(BLK) void cone_fused_kernel(
    const float* __restrict__ eyes,
    const float* __restrict__ v,
    const float* __restrict__ R,
    const float* __restrict__ t,
    const float* __restrict__ alpha,
    float* __restrict__ out,
    int B, int total4)
{
    // coeffs packed as 2x float4 per row: {s00,s11,s22,2s01} {2s02,2s12,-,-}
    // padded to 257 rows so the unconditional row+1 read stays in-bounds
    __shared__ v4f c4[2 * (NB + 1)];
    const int tid = threadIdx.x;
    const int b0  = blockIdx.x * NB;
    const int b   = b0 + tid;

    // ---- Phase 1: every thread builds one row's quadratic-form coefficients ----
    if (b < B) {
        float vx = v[b*3+0], vy = v[b*3+1], vz = v[b*3+2];
        float n  = sqrtf(vx*vx + vy*vy + vz*vz);
        n = fmaxf(n, 1e-14f);
        const float inv = 1.0f / n;
        vx *= inv; vy *= inv; vz *= inv;
        const float a = alpha[b];

        // W rows: w0 = R[:,0], w1 = R[:,1], w2 = t - eyes  (R row-major [3][3])
        const float* Rb = R + (size_t)b * 9;
        const float w0x = Rb[0], w0y = Rb[3], w0z = Rb[6];
        const float w1x = Rb[1], w1y = Rb[4], w1z = Rb[7];
        const float w2x = t[b*3+0] - eyes[b*3+0];
        const float w2y = t[b*3+1] - eyes[b*3+1];
        const float w2z = t[b*3+2] - eyes[b*3+2];

        // sigma[a][c] = (vn.w_a)(vn.w_c) - alpha*(w_a.w_c)
        const float d0 = vx*w0x + vy*w0y + vz*w0z;
        const float d1 = vx*w1x + vy*w1y + vz*w1z;
        const float d2 = vx*w2x + vy*w2y + vz*w2z;

        const float s00 = d0*d0 - a*(w0x*w0x + w0y*w0y + w0z*w0z);
        const float s11 = d1*d1 - a*(w1x*w1x + w1y*w1y + w1z*w1z);
        const float s22 = d2*d2 - a*(w2x*w2x + w2y*w2y + w2z*w2z);
        const float t01 = 2.0f * (d0*d1 - a*(w0x*w1x + w0y*w1y + w0z*w1z));
        const float t02 = 2.0f * (d0*d2 - a*(w0x*w2x + w0y*w2y + w0z*w2z));
        const float t12 = 2.0f * (d1*d2 - a*(w1x*w2x + w1y*w2y + w1z*w2z));

        v4f lo = {s00, s11, s22, t01};
        v4f hi = {t02, t12, 0.0f, 0.0f};
        c4[2*tid+0] = lo;
        c4[2*tid+1] = hi;
    }
    __syncthreads();

    // ---- Phase 2: 10816 coalesced nontemporal float4 stores per block ----
    // Per wave-iteration, lanes span 256 floats -> <=2 distinct rows -> LDS
    // reads are broadcasts (conflict-free).
    const size_t base4 = (size_t)blockIdx.x * NV4;
    for (int it = 0; it < NIT; ++it) {
        const int idx = it * BLK + tid;          // local float4 index, < 10816
        if (idx < NV4 && (int)(base4 + idx) < total4) {
            const int lfl = idx * 4;             // local float index, < 43264
            // row = lfl/169 : magic m=1626496491, m*169-2^38=35, exact for n<2^38/35
            int row = (int)(((unsigned long long)lfl * 1626496491ULL) >> 38);
            int k0  = lfl - 169 * row;

            const v4f alo = c4[2*row+0];
            const v4f ahi = c4[2*row+1];
            const v4f blo = c4[2*row+2];         // row+1 (pad row never selected)
            const v4f bhi = c4[2*row+3];

            v4f rv;
            #pragma unroll
            for (int e = 0; e < 4; ++e) {
                const int kk  = k0 + e;
                const bool nx = (kk >= 169);     // crossed into row+1
                const int k   = nx ? kk - 169 : kk;
                const float s00 = nx ? blo.x : alo.x;
                const float s11 = nx ? blo.y : alo.y;
                const float s22 = nx ? blo.z : alo.z;
                const float t01 = nx ? blo.w : alo.w;
                const float t02 = nx ? bhi.x : ahi.x;
                const float t12 = nx ? bhi.y : ahi.y;
                // iq = k/13 exact for k<169 (20165*13 = 2^18+1); j = k%13
                const int iq = (k * 20165) >> 18;
                const int j  = k - 13 * iq;
                const float px = (float)(iq - 6) * (1.0f / 6.0f);
                const float py = (float)(j  - 6) * (1.0f / 6.0f);
                rv[e] = s22 + px * (s00 * px + t01 * py + t02)
                            + py * (s11 * py + t12);
            }
            __builtin_nontemporal_store(rv, (v4f*)out + base4 + idx);
        }
    }
}

extern "C" void kernel_launch(void* const* d_in, const int* in_sizes, int n_in,
                              void* d_out, int out_size, void* d_ws, size_t ws_size,
                              hipStream_t stream) {
    const float* eyes  = (const float*)d_in[0];
    const float* v     = (const float*)d_in[1];
    const float* R     = (const float*)d_in[2];
    const float* t     = (const float*)d_in[3];
    const float* alpha = (const float*)d_in[4];
    float* out = (float*)d_out;

    const int B = in_sizes[4];                 // alpha has B elements
    const int total4 = out_size / 4;           // B*169/4 float4s
    const int grid = (B + NB - 1) / NB;        // 512 blocks for B=131072

    cone_fused_kernel<<<grid, BLK, 0, stream>>>(eyes, v, R, t, alpha, out, B, total4);
}